// Round 1
// baseline (416.748 us; speedup 1.0000x reference)
//
#include <hip/hip_runtime.h>

typedef unsigned short u16;
typedef __bf16 bf16x8 __attribute__((ext_vector_type(8)));
typedef float f32x4 __attribute__((ext_vector_type(4)));

#define AS1 __attribute__((address_space(1)))
#define AS3 __attribute__((address_space(3)))

__device__ inline u16 f2bf(float f) {
    union { float f; unsigned u; } c; c.f = f;
    unsigned u = c.u;
    u += 0x7fffu + ((u >> 16) & 1u);   // round-to-nearest-even
    return (u16)(u >> 16);
}
__device__ inline float bf2f(u16 b) {
    union { unsigned u; float f; } c; c.u = ((unsigned)b) << 16;
    return c.f;
}

__device__ inline void async_cp16(const void* g, void* l) {
    __builtin_amdgcn_global_load_lds((const AS1 void*)g, (AS3 void*)l, 16, 0, 0);
}

// ---------------------------------------------------------------------------
// fp32 -> bf16 conversion, 4 elems/thread
// ---------------------------------------------------------------------------
__global__ __launch_bounds__(256)
void f32_to_bf16_k(const float* __restrict__ src, u16* __restrict__ dst, int n) {
    int i = (blockIdx.x * 256 + threadIdx.x) * 4;
    if (i + 3 >= n) {
        for (int j = i; j < n; j++) dst[j] = f2bf(src[j]);
        return;
    }
    float4 f = *(const float4*)(src + i);
    union { u16 h[4]; uint2 v; } o;
    o.h[0] = f2bf(f.x); o.h[1] = f2bf(f.y);
    o.h[2] = f2bf(f.z); o.h[3] = f2bf(f.w);
    *(uint2*)(dst + i) = o.v;
}

// ---------------------------------------------------------------------------
// GEMM: C[m][n] = sum_k A[m][k] * B[n][k]   (both row-major, K contiguous)
// m97 structure: 128x128 tile, BK=32, 4 waves (2x2 of 64x64), 16x16x32 MFMA,
// global_load_lds width=16 staging, single-buffered LDS with 2 barriers.
// M, N multiples of 128; K multiple of 32 (true for all our shapes).
// ---------------------------------------------------------------------------
template <bool BF16_OUT>
__global__ __launch_bounds__(256)
void gemm_bt(const u16* __restrict__ A, const u16* __restrict__ B,
             void* __restrict__ Cout, int N, int K) {
    __shared__ u16 ldsA[128 * 32];
    __shared__ u16 ldsB[128 * 32];

    const int tid  = threadIdx.x;
    const int wave = tid >> 6;
    const int lane = tid & 63;
    const int row0 = blockIdx.x * 128;
    const int col0 = blockIdx.y * 128;
    const int waveM = (wave >> 1) * 64;
    const int waveN = (wave & 1) * 64;
    const int lm   = lane & 15;   // row (A) / col (B) within a 16-tile
    const int quad = lane >> 4;   // k-group selector

    // staging: thread t covers LDS bytes [t*16, t*16+16) per 64-row half-tile
    const int stRow = wave * 16 + (lane >> 2);   // 0..63
    const int stCol = (lane & 3) * 8;            // 0,8,16,24
    const u16* gA = A + (size_t)(row0 + stRow) * K + stCol;
    const u16* gB = B + (size_t)(col0 + stRow) * K + stCol;
    char* lA = (char*)ldsA + wave * 1024;        // wave-uniform LDS base
    char* lB = (char*)ldsB + wave * 1024;

    f32x4 acc[4][4];
#pragma unroll
    for (int i = 0; i < 4; i++)
#pragma unroll
        for (int j = 0; j < 4; j++) acc[i][j] = (f32x4){0.f, 0.f, 0.f, 0.f};

    for (int kb = 0; kb < K; kb += 32) {
        async_cp16(gA + kb,                    lA);
        async_cp16(gA + (size_t)64 * K + kb,   lA + 4096);
        async_cp16(gB + kb,                    lB);
        async_cp16(gB + (size_t)64 * K + kb,   lB + 4096);
        __syncthreads();   // drains vmcnt(0): staged data visible

        bf16x8 af[4], bg[4];
#pragma unroll
        for (int mi = 0; mi < 4; mi++)
            af[mi] = *(const bf16x8*)(ldsA + (waveM + mi * 16 + lm) * 32 + quad * 8);
#pragma unroll
        for (int ni = 0; ni < 4; ni++)
            bg[ni] = *(const bf16x8*)(ldsB + (waveN + ni * 16 + lm) * 32 + quad * 8);

#pragma unroll
        for (int mi = 0; mi < 4; mi++)
#pragma unroll
            for (int ni = 0; ni < 4; ni++)
                acc[mi][ni] = __builtin_amdgcn_mfma_f32_16x16x32_bf16(
                    af[mi], bg[ni], acc[mi][ni], 0, 0, 0);
        __syncthreads();   // protect LDS before next stage overwrites
    }

    // epilogue: C/D layout col = lane&15, row = quad*4 + reg
    const int rbase = row0 + waveM + quad * 4;
    const int cbase = col0 + waveN + lm;
    if (BF16_OUT) {
        u16* C = (u16*)Cout;
#pragma unroll
        for (int mi = 0; mi < 4; mi++)
#pragma unroll
            for (int r = 0; r < 4; r++) {
                size_t ro = (size_t)(rbase + mi * 16 + r) * N;
#pragma unroll
                for (int ni = 0; ni < 4; ni++)
                    C[ro + cbase + ni * 16] = f2bf(acc[mi][ni][r]);
            }
    } else {
        float* C = (float*)Cout;
#pragma unroll
        for (int mi = 0; mi < 4; mi++)
#pragma unroll
            for (int r = 0; r < 4; r++) {
                size_t ro = (size_t)(rbase + mi * 16 + r) * N;
#pragma unroll
                for (int ni = 0; ni < 4; ni++)
                    C[ro + cbase + ni * 16] = acc[mi][ni][r];
            }
    }
}

// ---------------------------------------------------------------------------
// Per-token attention. qkv row layout: [q(2048) | k(512) | v(512)] bf16.
// RoPE dropped (score-invariant); 4x head repeat collapsed to softmax over 8.
// One block (256 thr) per token: thread t -> head h=t>>3, d-segment j=t&7.
// ---------------------------------------------------------------------------
__global__ __launch_bounds__(256)
void attn_tok(const u16* __restrict__ qkv, u16* __restrict__ out) {
    __shared__ float kvf[1024];   // k (512 floats) then v (512 floats)
    const int tok = blockIdx.x;
    const int t = threadIdx.x;
    const u16* qrow = qkv + (size_t)tok * 3072;

    {   // stage k|v (contiguous 1024 bf16) into LDS as fp32
        uint2 w = *(const uint2*)(qrow + 2048 + t * 4);
        kvf[t * 4 + 0] = bf2f((u16)(w.x & 0xffff));
        kvf[t * 4 + 1] = bf2f((u16)(w.x >> 16));
        kvf[t * 4 + 2] = bf2f((u16)(w.y & 0xffff));
        kvf[t * 4 + 3] = bf2f((u16)(w.y >> 16));
    }
    __syncthreads();

    const int h = t >> 3, j = t & 7;
    float qf[8];
    {
        uint4 w = *(const uint4*)(qrow + h * 64 + j * 8);
        unsigned ws4[4] = {w.x, w.y, w.z, w.w};
#pragma unroll
        for (int i = 0; i < 4; i++) {
            qf[2 * i]     = bf2f((u16)(ws4[i] & 0xffff));
            qf[2 * i + 1] = bf2f((u16)(ws4[i] >> 16));
        }
    }

    float s[8];
#pragma unroll
    for (int g = 0; g < 8; g++) {
        const float* kk = kvf + g * 64 + j * 8;
        float a = 0.f;
#pragma unroll
        for (int d = 0; d < 8; d++) a += qf[d] * kk[d];
        s[g] = a;
    }
    // reduce partial dots across the 8 lanes of this head (lanes share wave)
#pragma unroll
    for (int g = 0; g < 8; g++) {
        s[g] += __shfl_xor(s[g], 1);
        s[g] += __shfl_xor(s[g], 2);
        s[g] += __shfl_xor(s[g], 4);
    }
    float m = -1e30f;
#pragma unroll
    for (int g = 0; g < 8; g++) { s[g] *= 0.125f; m = fmaxf(m, s[g]); }
    float p[8], l = 0.f;
#pragma unroll
    for (int g = 0; g < 8; g++) { p[g] = __expf(s[g] - m); l += p[g]; }
    float rl = 1.f / l;

    float o[8] = {0, 0, 0, 0, 0, 0, 0, 0};
#pragma unroll
    for (int g = 0; g < 8; g++) {
        float w = p[g] * rl;
        const float* vv = kvf + 512 + g * 64 + j * 8;
#pragma unroll
        for (int d = 0; d < 8; d++) o[d] += w * vv[d];
    }

    unsigned po[4];
#pragma unroll
    for (int i = 0; i < 4; i++)
        po[i] = (unsigned)f2bf(o[2 * i]) | ((unsigned)f2bf(o[2 * i + 1]) << 16);
    uint4 wo_; wo_.x = po[0]; wo_.y = po[1]; wo_.z = po[2]; wo_.w = po[3];
    *(uint4*)(out + (size_t)tok * 2048 + h * 64 + j * 8) = wo_;
}

// ---------------------------------------------------------------------------
// B=4, S=2048, DIM=2048, H=32, KVH=8, HD=64. Tokens M = 8192.
// Workspace layout (u16 elems): x_bf 16777216 | wqkv 6291456 | wo_bf 4194304
//                               | qkv 25165824 | attn 16777216  (138.4 MB)
// ---------------------------------------------------------------------------
extern "C" void kernel_launch(void* const* d_in, const int* in_sizes, int n_in,
                              void* d_out, int out_size, void* d_ws, size_t ws_size,
                              hipStream_t stream) {
    const float* x  = (const float*)d_in[0];
    const float* wq = (const float*)d_in[1];
    const float* wk = (const float*)d_in[2];
    const float* wv = (const float*)d_in[3];
    const float* wo = (const float*)d_in[4];
    // d_in[5], d_in[6] (freqs_cos/sin) intentionally unused: RoPE is a no-op
    // for this reference (same-position q/k rotation cancels in the dot).

    u16* x_bf  = (u16*)d_ws;
    u16* wqkv  = x_bf  + 16777216;   // wq rows 0..2047, wk 2048..2559, wv 2560..3071
    u16* wo_bf = wqkv  + 6291456;
    u16* qkv   = wo_bf + 4194304;    // 8192 x 3072
    u16* attn  = qkv   + 25165824;   // 8192 x 2048

    dim3 blk(256);
    f32_to_bf16_k<<<16384, blk, 0, stream>>>(x,  x_bf,            16777216);
    f32_to_bf16_k<<< 4096, blk, 0, stream>>>(wq, wqkv,             4194304);
    f32_to_bf16_k<<< 1024, blk, 0, stream>>>(wk, wqkv + 4194304,   1048576);
    f32_to_bf16_k<<< 1024, blk, 0, stream>>>(wv, wqkv + 5242880,   1048576);
    f32_to_bf16_k<<< 4096, blk, 0, stream>>>(wo, wo_bf,            4194304);

    // fused QKV projection: [8192 x 2048] x [3072 x 2048]^T -> [8192 x 3072]
    gemm_bt<true><<<dim3(64, 24), blk, 0, stream>>>(x_bf, wqkv, qkv, 3072, 2048);

    attn_tok<<<8192, blk, 0, stream>>>(qkv, attn);

    // output projection: [8192 x 2048] x [2048 x 2048]^T -> fp32 d_out
    gemm_bt<false><<<dim3(64, 16), blk, 0, stream>>>(attn, wo_bf, (float*)d_out,
                                                     2048, 2048);
}

// Round 2
// 375.101 us; speedup vs baseline: 1.1110x; 1.1110x over previous
//
#include <hip/hip_runtime.h>

typedef unsigned short u16;
typedef __bf16 bf16x8 __attribute__((ext_vector_type(8)));
typedef float f32x4 __attribute__((ext_vector_type(4)));

#define AS1 __attribute__((address_space(1)))
#define AS3 __attribute__((address_space(3)))

__device__ inline u16 f2bf(float f) {
    union { float f; unsigned u; } c; c.f = f;
    unsigned u = c.u;
    u += 0x7fffu + ((u >> 16) & 1u);   // round-to-nearest-even
    return (u16)(u >> 16);
}
__device__ inline float bf2f(u16 b) {
    union { unsigned u; float f; } c; c.u = ((unsigned)b) << 16;
    return c.f;
}

__device__ inline void async_cp16(const void* g, void* l) {
    __builtin_amdgcn_global_load_lds((const AS1 void*)g, (AS3 void*)l, 16, 0, 0);
}

// ---------------------------------------------------------------------------
// fp32 -> bf16, 8 elems/thread (x activation: 16777216 elems)
// ---------------------------------------------------------------------------
__global__ __launch_bounds__(256)
void f32_to_bf16_x8(const float* __restrict__ src, u16* __restrict__ dst) {
    int i = (blockIdx.x * 256 + threadIdx.x) * 8;
    float4 f0 = *(const float4*)(src + i);
    float4 f1 = *(const float4*)(src + i + 4);
    union { u16 h[8]; uint4 v; } o;
    o.h[0] = f2bf(f0.x); o.h[1] = f2bf(f0.y);
    o.h[2] = f2bf(f0.z); o.h[3] = f2bf(f0.w);
    o.h[4] = f2bf(f1.x); o.h[5] = f2bf(f1.y);
    o.h[6] = f2bf(f1.z); o.h[7] = f2bf(f1.w);
    *(uint4*)(dst + i) = o.v;
}

// ---------------------------------------------------------------------------
// All four weight matrices in ONE launch.
// Segments (u16 dst elems): wq->wqkv[0,4194304) wk->wqkv[+1048576)
//                           wv->wqkv[+1048576)  wo->wo_bf[0,4194304)
// Total 10485760 elems, 4/thread, 10240 blocks. All boundaries %4==0.
// ---------------------------------------------------------------------------
__global__ __launch_bounds__(256)
void conv_weights(const float* __restrict__ wq, const float* __restrict__ wk,
                  const float* __restrict__ wv, const float* __restrict__ wo,
                  u16* __restrict__ wqkv, u16* __restrict__ wo_bf) {
    int i = (blockIdx.x * 256 + threadIdx.x) * 4;
    const float* src;
    u16* dst;
    if (i < 4194304)       { src = wq + i;           dst = wqkv + i; }
    else if (i < 5242880)  { src = wk + (i-4194304); dst = wqkv + i; }
    else if (i < 6291456)  { src = wv + (i-5242880); dst = wqkv + i; }
    else                   { src = wo + (i-6291456); dst = wo_bf + (i-6291456); }
    float4 f = *(const float4*)src;
    union { u16 h[4]; uint2 v; } o;
    o.h[0] = f2bf(f.x); o.h[1] = f2bf(f.y);
    o.h[2] = f2bf(f.z); o.h[3] = f2bf(f.w);
    *(uint2*)dst = o.v;
}

// ---------------------------------------------------------------------------
// GEMM: C[m][n] = sum_k A[m][k]*B[n][k]  (row-major, K contiguous)
// 128x128 tile, BK=64 (half the barriers of BK=32), 4 waves (2x2 of 64x64),
// 16x16x32 bf16 MFMA, global_load_lds width=16 staging.
// LDS tiles 128 rows x 64 u16 (128 B row), XOR-chunk-swizzled:
//   LDS[r][chunk p] = global[r][chunk p ^ (r&7)]   (chunk = 16 B)
// Staging lane l of wave w, inst i: row = 32i+8w+(l>>3)  (row&7 == l>>3),
//   LDS pos chunk l&7 -> load global chunk (l&7)^(l>>3). Coalescing kept
//   (8-lane runs permute within one 128-B segment).
// Fragment read row = waveM+mi*16+lm (row&7 == lm&7), k-half s, chunk
//   g=4s+quad -> LDS chunk g^(lm&7). Every 8-lane phase hits 8 distinct
//   bank groups -> conflict-free.
// Requires: M,N %128==0, K %64==0.
// ---------------------------------------------------------------------------
template <bool BF16_OUT>
__global__ __launch_bounds__(256)
void gemm_bt(const u16* __restrict__ A, const u16* __restrict__ B,
             void* __restrict__ Cout, int N, int K) {
    __shared__ u16 ldsA[128 * 64];
    __shared__ u16 ldsB[128 * 64];

    const int tid  = threadIdx.x;
    const int wave = tid >> 6;
    const int lane = tid & 63;
    const int row0 = blockIdx.x * 128;
    const int col0 = blockIdx.y * 128;
    const int waveM = (wave >> 1) * 64;
    const int waveN = (wave & 1) * 64;
    const int lm   = lane & 15;
    const int quad = lane >> 4;

    // staging addresses
    const int sr  = lane >> 3;                       // row&7 within 8-row group
    const int stR = 8 * wave + sr;                   // + 32*i per instruction
    const int stC = ((lane & 7) ^ sr) * 8;           // swizzled u16 col in k-slice
    const u16* gA = A + (size_t)(row0 + stR) * K + stC;
    const u16* gB = B + (size_t)(col0 + stR) * K + stC;
    char* lA = (char*)ldsA + wave * 1024;            // wave-uniform base, inst 0
    char* lB = (char*)ldsB + wave * 1024;
    const size_t g32K = (size_t)32 * K;

    f32x4 acc[4][4];
#pragma unroll
    for (int i = 0; i < 4; i++)
#pragma unroll
        for (int j = 0; j < 4; j++) acc[i][j] = (f32x4){0.f, 0.f, 0.f, 0.f};

    // fragment LDS byte offsets (constant across k-loop)
    int aOff[2][4], bOff[2][4];
#pragma unroll
    for (int s = 0; s < 2; s++)
#pragma unroll
        for (int mi = 0; mi < 4; mi++) {
            int rA = waveM + mi * 16 + lm;
            int rB = waveN + mi * 16 + lm;
            int c  = (4 * s + quad) ^ (lm & 7);
            aOff[s][mi] = rA * 128 + c * 16;
            bOff[s][mi] = rB * 128 + c * 16;
        }

    for (int kb = 0; kb < K; kb += 64) {
#pragma unroll
        for (int i = 0; i < 4; i++)
            async_cp16(gA + i * g32K + kb, lA + i * 4096);
#pragma unroll
        for (int i = 0; i < 4; i++)
            async_cp16(gB + i * g32K + kb, lB + i * 4096);
        __syncthreads();   // drains vmcnt(0): staged data visible

#pragma unroll
        for (int s = 0; s < 2; s++) {
            bf16x8 af[4], bg[4];
#pragma unroll
            for (int mi = 0; mi < 4; mi++)
                af[mi] = *(const bf16x8*)((const char*)ldsA + aOff[s][mi]);
#pragma unroll
            for (int ni = 0; ni < 4; ni++)
                bg[ni] = *(const bf16x8*)((const char*)ldsB + bOff[s][ni]);
#pragma unroll
            for (int mi = 0; mi < 4; mi++)
#pragma unroll
                for (int ni = 0; ni < 4; ni++)
                    acc[mi][ni] = __builtin_amdgcn_mfma_f32_16x16x32_bf16(
                        af[mi], bg[ni], acc[mi][ni], 0, 0, 0);
        }
        __syncthreads();   // protect LDS before next stage overwrites
    }

    // epilogue: C/D layout col = lane&15, row = quad*4 + reg
    const int rbase = row0 + waveM + quad * 4;
    const int cbase = col0 + waveN + lm;
    if (BF16_OUT) {
        u16* C = (u16*)Cout;
#pragma unroll
        for (int mi = 0; mi < 4; mi++)
#pragma unroll
            for (int r = 0; r < 4; r++) {
                size_t ro = (size_t)(rbase + mi * 16 + r) * N;
#pragma unroll
                for (int ni = 0; ni < 4; ni++)
                    C[ro + cbase + ni * 16] = f2bf(acc[mi][ni][r]);
            }
    } else {
        float* C = (float*)Cout;
#pragma unroll
        for (int mi = 0; mi < 4; mi++)
#pragma unroll
            for (int r = 0; r < 4; r++) {
                size_t ro = (size_t)(rbase + mi * 16 + r) * N;
#pragma unroll
                for (int ni = 0; ni < 4; ni++)
                    C[ro + cbase + ni * 16] = acc[mi][ni][r];
            }
    }
}

// ---------------------------------------------------------------------------
// Per-token attention. qkv row: [q(2048) | k(512) | v(512)] bf16.
// RoPE dropped (same-position q/k rotation cancels in the dot);
// 4x head repeat collapsed (softmax over 8 distinct kv-heads).
// One block per token: thread t -> head h=t>>3, d-segment j=t&7.
// ---------------------------------------------------------------------------
__global__ __launch_bounds__(256)
void attn_tok(const u16* __restrict__ qkv, u16* __restrict__ out) {
    __shared__ float kvf[1024];   // k (512 floats) then v (512 floats)
    const int tok = blockIdx.x;
    const int t = threadIdx.x;
    const u16* qrow = qkv + (size_t)tok * 3072;

    {   // stage k|v (contiguous 1024 bf16) into LDS as fp32
        uint2 w = *(const uint2*)(qrow + 2048 + t * 4);
        kvf[t * 4 + 0] = bf2f((u16)(w.x & 0xffff));
        kvf[t * 4 + 1] = bf2f((u16)(w.x >> 16));
        kvf[t * 4 + 2] = bf2f((u16)(w.y & 0xffff));
        kvf[t * 4 + 3] = bf2f((u16)(w.y >> 16));
    }
    __syncthreads();

    const int h = t >> 3, j = t & 7;
    float qf[8];
    {
        uint4 w = *(const uint4*)(qrow + h * 64 + j * 8);
        unsigned ws4[4] = {w.x, w.y, w.z, w.w};
#pragma unroll
        for (int i = 0; i < 4; i++) {
            qf[2 * i]     = bf2f((u16)(ws4[i] & 0xffff));
            qf[2 * i + 1] = bf2f((u16)(ws4[i] >> 16));
        }
    }

    float s[8];
#pragma unroll
    for (int g = 0; g < 8; g++) {
        const float* kk = kvf + g * 64 + j * 8;
        float a = 0.f;
#pragma unroll
        for (int d = 0; d < 8; d++) a += qf[d] * kk[d];
        s[g] = a;
    }
#pragma unroll
    for (int g = 0; g < 8; g++) {   // reduce across the head's 8 lanes
        s[g] += __shfl_xor(s[g], 1);
        s[g] += __shfl_xor(s[g], 2);
        s[g] += __shfl_xor(s[g], 4);
    }
    float m = -1e30f;
#pragma unroll
    for (int g = 0; g < 8; g++) { s[g] *= 0.125f; m = fmaxf(m, s[g]); }
    float p[8], l = 0.f;
#pragma unroll
    for (int g = 0; g < 8; g++) { p[g] = __expf(s[g] - m); l += p[g]; }
    float rl = 1.f / l;

    float o[8] = {0, 0, 0, 0, 0, 0, 0, 0};
#pragma unroll
    for (int g = 0; g < 8; g++) {
        float w = p[g] * rl;
        const float* vv = kvf + 512 + g * 64 + j * 8;
#pragma unroll
        for (int d = 0; d < 8; d++) o[d] += w * vv[d];
    }

    unsigned po[4];
#pragma unroll
    for (int i = 0; i < 4; i++)
        po[i] = (unsigned)f2bf(o[2 * i]) | ((unsigned)f2bf(o[2 * i + 1]) << 16);
    uint4 wo_; wo_.x = po[0]; wo_.y = po[1]; wo_.z = po[2]; wo_.w = po[3];
    *(uint4*)(out + (size_t)tok * 2048 + h * 64 + j * 8) = wo_;
}

// ---------------------------------------------------------------------------
// B=4, S=2048, DIM=2048, H=32, KVH=8, HD=64. Tokens M = 8192.
// Workspace (u16 elems): x_bf 16777216 | wqkv 6291456 | wo_bf 4194304
//                        | qkv 25165824 | attn 16777216  (138.4 MB)
// ---------------------------------------------------------------------------
extern "C" void kernel_launch(void* const* d_in, const int* in_sizes, int n_in,
                              void* d_out, int out_size, void* d_ws, size_t ws_size,
                              hipStream_t stream) {
    const float* x  = (const float*)d_in[0];
    const float* wq = (const float*)d_in[1];
    const float* wk = (const float*)d_in[2];
    const float* wv = (const float*)d_in[3];
    const float* wo = (const float*)d_in[4];
    // d_in[5]/d_in[6] (freqs_cos/sin) unused: RoPE cancels in same-position dots.

    u16* x_bf  = (u16*)d_ws;
    u16* wqkv  = x_bf  + 16777216;
    u16* wo_bf = wqkv  + 6291456;
    u16* qkv   = wo_bf + 4194304;    // 8192 x 3072
    u16* attn  = qkv   + 25165824;   // 8192 x 2048

    dim3 blk(256);
    f32_to_bf16_x8<<<8192, blk, 0, stream>>>(x, x_bf);
    conv_weights<<<10240, blk, 0, stream>>>(wq, wk, wv, wo, wqkv, wo_bf);

    // fused QKV projection: [8192 x 2048] x [3072 x 2048]^T -> [8192 x 3072]
    gemm_bt<true><<<dim3(64, 24), blk, 0, stream>>>(x_bf, wqkv, qkv, 3072, 2048);

    attn_tok<<<8192, blk, 0, stream>>>(qkv, attn);

    // output projection: [8192 x 2048] x [2048 x 2048]^T -> fp32 d_out
    gemm_bt<false><<<dim3(64, 16), blk, 0, stream>>>(attn, wo_bf, (float*)d_out,
                                                     2048, 2048);
}